// Round 2
// baseline (683.589 us; speedup 1.0000x reference)
//
#include <hip/hip_runtime.h>

// AUGRU fused scan, MI355X/gfx950.  R6: occupancy + chain-shortening.
//
// R5 post-mortem: 256us = ~3090 cy/step, Occupancy 11% (1 block/CU, 1 wave/
// SIMD) -> latency-bound lockstep scan; nothing hides LDS/MFMA/barrier-drain
// latency. 3.84M bank-conflict cycles from 4-way scalar b16 exchange; ub
// exchange forced wave-divergent phase 2.
//
// Changes:
//  - M_TILE=4, grid=1024 -> 4 blocks/CU (launch_bounds(256,4)); 4 independent
//    scan chains per SIMD hide each other's latency. MFMA rows 4..15 wasted
//    (MfmaUtil was 6% - irrelevant). LDS tiles zero-initialized once; scalar
//    writes guarded to lg==0 so garbage rows stay 0 (no NaN contamination).
//  - N re-partition: wave w owns gate r-tile w, gate u-tile 4+w, cand tile w.
//    u stays in registers at its h-update positions: ub array + exchange +
//    divergent phase-2 branch deleted.
//  - r*h sourced from hown registers (not hb): 8 scalar LDS reads/step gone.
//  - All swizzled LDS addresses hoisted; 2-deep x prefetch kept.
//
// Layouts (verified R5, absmax 0.0039): A/B frag k=(lane>>4)*8+j contiguous;
// C/D col=lane&15, row=(lane>>4)*4+reg. LDS tiles 16x64 f16, swizzle
// byte ^= (row&7)<<4.

typedef _Float16 half8_t __attribute__((ext_vector_type(8)));
typedef float    f32x4  __attribute__((ext_vector_type(4)));

#define T_MAX 200
#define H_DIM 64
#define M_TILE 4

__device__ __forceinline__ f32x4 mfma16(half8_t a, half8_t b, f32x4 c) {
    return __builtin_amdgcn_mfma_f32_16x16x32_f16(a, b, c, 0, 0, 0);
}
// byte address into a [16 rows][64 f16] LDS tile, bank-conflict swizzled
__device__ __forceinline__ int swz(int row, int byteInRow) {
    return (row * 128 + byteInRow) ^ ((row & 7) << 4);
}

__global__ __launch_bounds__(256, 4) void augru_mfma(
    const float* __restrict__ X,    // (B,200,64) fp32
    const int*   __restrict__ SL,   // (B,1) int32
    const float* __restrict__ ATT,  // (B,200,1) fp32
    const float* __restrict__ WG,   // (128,128) fp32
    const float* __restrict__ BG,   // (128,) fp32
    const float* __restrict__ WC,   // (128,64) fp32
    const float* __restrict__ BC,   // (64,) fp32
    float*       __restrict__ OUT)  // (B,200,64) fp32
{
    const int tid = threadIdx.x;
    const int w   = tid >> 6;      // wave 0..3
    const int l   = tid & 63;
    const int lr  = l & 15;        // A-frag row / C col
    const int lg  = l >> 4;        // frag k-group / C row-group
    const int b0  = blockIdx.x * M_TILE;

    __shared__ float    att_s[M_TILE][T_MAX];   // 3200 B
    __shared__ int      sl_s[M_TILE];
    __shared__ _Float16 xb[2][16 * 64];         // x(t) dbuf, swizzled
    __shared__ _Float16 hb[16 * 64];            // h(t), swizzled
    __shared__ _Float16 rhb[16 * 64];           // r*h, swizzled

    // ---- zero tiles once: rows >= M_TILE stay 0 forever (finite MFMA input)
    for (int i = tid; i < 16 * 64; i += 256) {
        xb[0][i] = (_Float16)0.f; xb[1][i] = (_Float16)0.f;
        hb[i]    = (_Float16)0.f; rhb[i]   = (_Float16)0.f;
    }
    {
        const float* ap = ATT + (size_t)(b0 + w) * T_MAX;
        for (int c = l; c < T_MAX; c += 64) att_s[w][c] = ap[c];
    }
    if (tid < M_TILE) {
        int v = SL[b0 + tid];
        sl_s[tid] = v < 0 ? 0 : (v > T_MAX ? T_MAX : v);
    }

    // ---- weights: wave w owns gate r-tile w, gate u-tile 4+w, cand tile w
    half8_t wgr[4], wgu[4], wcd[4];
    const int cr = 16 * w + lr;        // r col == cand col == output col
    const int cu = 64 + cr;            // u col in gate space
#pragma unroll
    for (int kt = 0; kt < 4; ++kt) {
        const int kb = 32 * kt + 8 * lg;
        half8_t fr, fu, fc;
#pragma unroll
        for (int j = 0; j < 8; ++j) {
            fr[j] = (_Float16)WG[(size_t)(kb + j) * 128 + cr];
            fu[j] = (_Float16)WG[(size_t)(kb + j) * 128 + cu];
            fc[j] = (_Float16)WC[(size_t)(kb + j) * 64 + cr];
        }
        wgr[kt] = fr; wgu[kt] = fu; wcd[kt] = fc;
    }
    const float bias_r = BG[cr], bias_u = BG[cu], bias_c = BC[cr];

    __syncthreads();                    // zero-init + sl_s visible

    // ---- stage x(0); preload x(1)
    const float* xcol = X + ((size_t)(b0 + w) * T_MAX) * 64 + l;  // stride 64/step
    const int a_stg = swz(w, 2 * l);
    *(_Float16*)((char*)xb[0] + a_stg) = (_Float16)xcol[0];
    float xv1 = xcol[64];               // x(1), always in-bounds

    __syncthreads();                    // x(0) published

    const int Lmax = max(max(sl_s[0], sl_s[1]), max(sl_s[2], sl_s[3]));
    int Lrow[M_TILE];
#pragma unroll
    for (int r = 0; r < M_TILE; ++r) Lrow[r] = sl_s[r];

    // hoisted LDS byte addresses
    const int a_f0 = swz(lr, 16 * lg);          // frag k-lo
    const int a_f1 = swz(lr, 64 + 16 * lg);     // frag k-hi
    int a_c[M_TILE];                            // scalar slots (row r, col cr)
#pragma unroll
    for (int r = 0; r < M_TILE; ++r) a_c[r] = swz(r, 2 * cr);

    float hown[M_TILE] = {0.f, 0.f, 0.f, 0.f};  // h at (row r, col cr), lg==0
    const size_t obase = (size_t)b0 * (T_MAX * H_DIM) + cr;

    for (int t = 0; t < Lmax; ++t) {
        const int pb = t & 1;
        int tn2 = t + 2; if (tn2 > T_MAX - 1) tn2 = T_MAX - 1;
        float xv2 = xcol[(size_t)tn2 * 64];     // prefetch x(t+2)

        // ---- phase 1: frags + gate MFMA + cand x-part
        char* xbase = (char*)xb[pb];
        half8_t ax0 = *(half8_t*)(xbase + a_f0);
        half8_t ax1 = *(half8_t*)(xbase + a_f1);
        half8_t ah0 = *(half8_t*)((char*)hb + a_f0);
        half8_t ah1 = *(half8_t*)((char*)hb + a_f1);

        f32x4 accr = {bias_r, bias_r, bias_r, bias_r};
        f32x4 accu = {bias_u, bias_u, bias_u, bias_u};
        f32x4 accc = {bias_c, bias_c, bias_c, bias_c};
        accr = mfma16(ax0, wgr[0], accr);  accu = mfma16(ax0, wgu[0], accu);
        accc = mfma16(ax0, wcd[0], accc);
        accr = mfma16(ax1, wgr[1], accr);  accu = mfma16(ax1, wgu[1], accu);
        accc = mfma16(ax1, wcd[1], accc);
        accr = mfma16(ah0, wgr[2], accr);  accu = mfma16(ah0, wgu[2], accu);
        accr = mfma16(ah1, wgr[3], accr);  accu = mfma16(ah1, wgu[3], accu);

        // ---- phase 2 (uniform): sigmoid, r*h -> rhb, u-hat in regs
        float uu[M_TILE];
        if (lg == 0) {
#pragma unroll
            for (int r = 0; r < M_TILE; ++r) {
                float rv = __fdividef(1.f, 1.f + __expf(-accr[r]));
                *(_Float16*)((char*)rhb + a_c[r]) = (_Float16)(rv * hown[r]);
                float a = att_s[r][t];
                uu[r] = (1.f - a) * __fdividef(1.f, 1.f + __expf(-accu[r]));
            }
        }
        __syncthreads();   // B2: rhb published

        // ---- phase 3: cand rh-part, tanh, update, stores
        half8_t ar0 = *(half8_t*)((char*)rhb + a_f0);
        half8_t ar1 = *(half8_t*)((char*)rhb + a_f1);
        accc = mfma16(ar0, wcd[2], accc);
        accc = mfma16(ar1, wcd[3], accc);

        if (lg == 0) {
#pragma unroll
            for (int r = 0; r < M_TILE; ++r) {
                float z  = accc[r];
                float az = fabsf(z);
                float e2 = __expf(2.f * az);
                float c  = copysignf(1.f - __fdividef(2.f, e2 + 1.f), z);
                float hn = uu[r] * hown[r] + (1.f - uu[r]) * c;
                bool  m  = (t < Lrow[r]);
                OUT[obase + (size_t)r * (T_MAX * H_DIM) + (size_t)t * H_DIM]
                    = m ? hn : 0.f;
                if (m) hown[r] = hn;
                *(_Float16*)((char*)hb + a_c[r]) = (_Float16)hown[r];
            }
        }

        // stage x(t+1) into the other buffer
        *(_Float16*)((char*)xb[pb ^ 1] + a_stg) = (_Float16)xv1;
        xv1 = xv2;
        __syncthreads();   // B3: hb(t+1), x(t+1) published
    }

    // ---- zero-fill masked tail t in [Lmax, 200), 16B stores
    {
        uint4 zz = make_uint4(0u, 0u, 0u, 0u);
        const int n4 = (T_MAX - Lmax) * (H_DIM / 4);
#pragma unroll
        for (int r = 0; r < M_TILE; ++r) {
            uint4* zp = (uint4*)(OUT + ((size_t)(b0 + r) * T_MAX + Lmax) * H_DIM);
            for (int i = tid; i < n4; i += 256) zp[i] = zz;
        }
    }
}

extern "C" void kernel_launch(void* const* d_in, const int* in_sizes, int n_in,
                              void* d_out, int out_size, void* d_ws, size_t ws_size,
                              hipStream_t stream) {
    const float* X   = (const float*)d_in[0];
    const int*   SL  = (const int*)d_in[1];
    const float* ATT = (const float*)d_in[2];
    const float* WG  = (const float*)d_in[3];
    const float* BG  = (const float*)d_in[4];
    const float* WC  = (const float*)d_in[5];
    const float* BC  = (const float*)d_in[6];
    float*       OUT = (float*)d_out;

    const int B = in_sizes[1];   // sequence_length has B*1 elements
    dim3 grid(B / M_TILE), block(256);
    augru_mfma<<<grid, block, 0, stream>>>(X, SL, ATT, WG, BG, WC, BC, OUT);
}

// Round 3
// 468.730 us; speedup vs baseline: 1.4584x; 1.4584x over previous
//
#include <hip/hip_runtime.h>

// AUGRU fused scan, MI355X/gfx950.  R7: dense M_TILE=16 + lgkm-only barriers.
//
// R6 post-mortem: M_TILE=4 quadrupled per-sequence VALU (masked lanes +
// unamortized overheads) -> VALU-issue-bound at 68% busy, 457us. Dense config
// is M_TILE=16 (R5). R5's 3090cy/step was stall-dominated: compiler emits
// s_waitcnt vmcnt(0) before every s_barrier, so the per-step x-prefetch
// global_load drained at HBM latency at the mid-step barrier, every step.
//
// Changes:
//  - M_TILE=16 (grid 256, 4 waves, all scalar phases dense over 256 lanes).
//  - N-partition from R6: wave w owns gate r-tile w, gate u-tile 4+w, cand
//    tile w. u stays in registers at its update positions; r*h comes from
//    hown registers. No ub array, no hb scalar reads, uniform phases.
//  - Scan-loop barriers are inline-asm "s_waitcnt lgkmcnt(0); s_barrier":
//    LDS publishes are protected; wave-private global traffic (x prefetch,
//    OUT stores) stays in flight across barriers (AITER counted-vmcnt idea).
//  - 2-deep x prefetch; all swizzled LDS addresses hoisted.
//
// Layouts (verified R5/R6, absmax 0.0039): A/B frag k=(lane>>4)*8+j
// contiguous; C/D col=lane&15, row=(lane>>4)*4+reg. LDS tiles 16x64 f16,
// swizzle byte ^= (row&7)<<4.

typedef _Float16 half4_t __attribute__((ext_vector_type(4)));
typedef _Float16 half8_t __attribute__((ext_vector_type(8)));
typedef float    f32x4  __attribute__((ext_vector_type(4)));

#define T_MAX 200
#define H_DIM 64
#define M_TILE 16

__device__ __forceinline__ f32x4 mfma16(half8_t a, half8_t b, f32x4 c) {
    return __builtin_amdgcn_mfma_f32_16x16x32_f16(a, b, c, 0, 0, 0);
}
// byte address into a [16 rows][64 f16] LDS tile, bank-conflict swizzled
__device__ __forceinline__ int swz(int row, int byteInRow) {
    return (row * 128 + byteInRow) ^ ((row & 7) << 4);
}
// Barrier that drains LDS only: global loads/stores stay in flight.
__device__ __forceinline__ void lgkm_barrier() {
    asm volatile("s_waitcnt lgkmcnt(0)\n\ts_barrier" ::: "memory");
}

__global__ __launch_bounds__(256, 1) void augru_mfma(
    const float* __restrict__ X,    // (B,200,64) fp32
    const int*   __restrict__ SL,   // (B,1) int32
    const float* __restrict__ ATT,  // (B,200,1) fp32
    const float* __restrict__ WG,   // (128,128) fp32
    const float* __restrict__ BG,   // (128,) fp32
    const float* __restrict__ WC,   // (128,64) fp32
    const float* __restrict__ BC,   // (64,) fp32
    float*       __restrict__ OUT)  // (B,200,64) fp32
{
    const int tid = threadIdx.x;
    const int w   = tid >> 6;      // wave 0..3
    const int l   = tid & 63;
    const int lr  = l & 15;        // A-frag row / C col
    const int lg  = l >> 4;        // frag k-group / C row-group
    const int b0  = blockIdx.x * M_TILE;

    __shared__ float    att_s[M_TILE][T_MAX];   // broadcast reads
    __shared__ int      sl_s[M_TILE];
    __shared__ _Float16 xb[2][16 * 64];         // x(t) dbuf, swizzled
    __shared__ _Float16 hb[16 * 64];            // h(t), swizzled
    __shared__ _Float16 rhb[16 * 64];           // r*h, swizzled

    // ---- prologue ----
#pragma unroll
    for (int k = 0; k < 4; ++k) {
        const int r = 4 * w + k;
        const float* ap = ATT + (size_t)(b0 + r) * T_MAX;
        for (int c = l; c < T_MAX; c += 64) att_s[r][c] = ap[c];
    }
    if (tid < M_TILE) {
        int v = SL[b0 + tid];
        sl_s[tid] = v < 0 ? 0 : (v > T_MAX ? T_MAX : v);
    }
    for (int i = tid; i < 16 * 64; i += 256) hb[i] = (_Float16)0.f;  // h(0)=0

    // ---- weights: wave w owns gate r-tile w, gate u-tile 4+w, cand tile w
    half8_t wgr[4], wgu[4], wcd[4];
    const int cr = 16 * w + lr;        // r col == cand col == output col
    const int cu = 64 + cr;            // u col in gate space
#pragma unroll
    for (int kt = 0; kt < 4; ++kt) {
        const int kb = 32 * kt + 8 * lg;
        half8_t fr, fu, fc;
#pragma unroll
        for (int j = 0; j < 8; ++j) {
            fr[j] = (_Float16)WG[(size_t)(kb + j) * 128 + cr];
            fu[j] = (_Float16)WG[(size_t)(kb + j) * 128 + cu];
            fc[j] = (_Float16)WC[(size_t)(kb + j) * 64 + cr];
        }
        wgr[kt] = fr; wgu[kt] = fu; wcd[kt] = fc;
    }
    const float bias_r = BG[cr], bias_u = BG[cu], bias_c = BC[cr];

    // ---- stage x(0); preload x(1) (thread (xr,xq) owns one float4) ----
    const int xr = tid >> 4, xq = tid & 15;
    const float* xptr = X + (size_t)(b0 + xr) * (T_MAX * H_DIM) + 4 * xq;
    const int a_stg = swz(xr, 8 * xq);
    {
        float4 v0 = *(const float4*)(xptr);
        half4_t h4 = { (_Float16)v0.x, (_Float16)v0.y, (_Float16)v0.z, (_Float16)v0.w };
        *(half4_t*)((char*)xb[0] + a_stg) = h4;
    }
    float4 xv1 = *(const float4*)(xptr + 1 * H_DIM);   // x(1)

    __syncthreads();   // prologue publish (full barrier once is fine)

    const int Lmax = max(
        max(max(sl_s[0], sl_s[1]), max(sl_s[2], sl_s[3])),
        max(max(max(sl_s[4], sl_s[5]), max(sl_s[6], sl_s[7])),
            max(max(sl_s[8], sl_s[9]), max(max(sl_s[10], sl_s[11]),
                max(max(sl_s[12], sl_s[13]), max(sl_s[14], sl_s[15]))))));
    int Lrow[4];
#pragma unroll
    for (int reg = 0; reg < 4; ++reg) Lrow[reg] = sl_s[4 * lg + reg];

    // hoisted LDS byte addresses
    const int a_f0 = swz(lr, 16 * lg);          // frag k-lo
    const int a_f1 = swz(lr, 64 + 16 * lg);     // frag k-hi
    int a_c[4];                                  // scalar slot (row 4lg+reg, col cr)
    size_t obase[4];
#pragma unroll
    for (int reg = 0; reg < 4; ++reg) {
        a_c[reg]   = swz(4 * lg + reg, 2 * cr);
        obase[reg] = (size_t)(b0 + 4 * lg + reg) * (T_MAX * H_DIM) + cr;
    }

    float hown[4] = {0.f, 0.f, 0.f, 0.f};   // h at (row 4lg+reg, col cr)

    for (int t = 0; t < Lmax; ++t) {
        const int pb = t & 1;
        int tn2 = t + 2; if (tn2 > T_MAX - 1) tn2 = T_MAX - 1;
        float4 xv2 = *(const float4*)(xptr + (size_t)tn2 * H_DIM);  // in flight

        // att broadcast reads, hoisted to top
        float attv[4];
#pragma unroll
        for (int reg = 0; reg < 4; ++reg) attv[reg] = att_s[4 * lg + reg][t];

        // ---- phase 1: frags + gate MFMA + cand x-part ----
        char* xbase = (char*)xb[pb];
        half8_t ax0 = *(half8_t*)(xbase + a_f0);
        half8_t ax1 = *(half8_t*)(xbase + a_f1);
        half8_t ah0 = *(half8_t*)((char*)hb + a_f0);
        half8_t ah1 = *(half8_t*)((char*)hb + a_f1);

        f32x4 accr = {bias_r, bias_r, bias_r, bias_r};
        f32x4 accu = {bias_u, bias_u, bias_u, bias_u};
        f32x4 accc = {bias_c, bias_c, bias_c, bias_c};
        accr = mfma16(ax0, wgr[0], accr);  accu = mfma16(ax0, wgu[0], accu);
        accc = mfma16(ax0, wcd[0], accc);
        accr = mfma16(ax1, wgr[1], accr);  accu = mfma16(ax1, wgu[1], accu);
        accc = mfma16(ax1, wcd[1], accc);
        accr = mfma16(ah0, wgr[2], accr);  accu = mfma16(ah0, wgu[2], accu);
        accr = mfma16(ah1, wgr[3], accr);  accu = mfma16(ah1, wgu[3], accu);

        // ---- phase 2 (dense, uniform): sigmoid, r*h -> rhb, u-hat in regs
        float uu[4];
#pragma unroll
        for (int reg = 0; reg < 4; ++reg) {
            float rv = __fdividef(1.f, 1.f + __expf(-accr[reg]));
            *(_Float16*)((char*)rhb + a_c[reg]) = (_Float16)(rv * hown[reg]);
            uu[reg] = (1.f - attv[reg]) * __fdividef(1.f, 1.f + __expf(-accu[reg]));
        }
        lgkm_barrier();   // B2: rhb published (LDS only; x prefetch stays in flight)

        // ---- phase 3: cand rh-part, tanh, update, store ----
        half8_t ar0 = *(half8_t*)((char*)rhb + a_f0);
        half8_t ar1 = *(half8_t*)((char*)rhb + a_f1);
        accc = mfma16(ar0, wcd[2], accc);
        accc = mfma16(ar1, wcd[3], accc);

#pragma unroll
        for (int reg = 0; reg < 4; ++reg) {
            float z  = accc[reg];
            float az = fabsf(z);
            float e2 = __expf(2.f * az);
            float c  = copysignf(1.f - __fdividef(2.f, e2 + 1.f), z);
            float hn = uu[reg] * hown[reg] + (1.f - uu[reg]) * c;
            bool  m  = (t < Lrow[reg]);
            OUT[obase[reg] + (size_t)t * H_DIM] = m ? hn : 0.f;
            if (m) hown[reg] = hn;
            *(_Float16*)((char*)hb + a_c[reg]) = (_Float16)hown[reg];
        }

        // stage x(t+1) into the other buffer
        {
            half4_t h4 = { (_Float16)xv1.x, (_Float16)xv1.y, (_Float16)xv1.z, (_Float16)xv1.w };
            *(half4_t*)((char*)xb[pb ^ 1] + a_stg) = h4;
        }
        xv1 = xv2;
        lgkm_barrier();   // B3: hb(t+1) + x(t+1) published
    }

    // ---- zero-fill masked tail t in [Lmax, 200), 16B stores ----
    {
        uint4 zz = make_uint4(0u, 0u, 0u, 0u);
        const int n4 = (T_MAX - Lmax) * (H_DIM / 4);
#pragma unroll
        for (int r = 0; r < M_TILE; ++r) {
            uint4* zp = (uint4*)(OUT + ((size_t)(b0 + r) * T_MAX + Lmax) * H_DIM);
            for (int i = tid; i < n4; i += 256) zp[i] = zz;
        }
    }
}

extern "C" void kernel_launch(void* const* d_in, const int* in_sizes, int n_in,
                              void* d_out, int out_size, void* d_ws, size_t ws_size,
                              hipStream_t stream) {
    const float* X   = (const float*)d_in[0];
    const int*   SL  = (const int*)d_in[1];
    const float* ATT = (const float*)d_in[2];
    const float* WG  = (const float*)d_in[3];
    const float* BG  = (const float*)d_in[4];
    const float* WC  = (const float*)d_in[5];
    const float* BC  = (const float*)d_in[6];
    float*       OUT = (float*)d_out;

    const int B = in_sizes[1];   // sequence_length has B*1 elements
    dim3 grid(B / M_TILE), block(256);
    augru_mfma<<<grid, block, 0, stream>>>(X, SL, ATT, WG, BG, WC, BC, OUT);
}